// Round 2
// baseline (1061.989 us; speedup 1.0000x reference)
//
#include <hip/hip_runtime.h>

// OT_GNN: 2x GCN -> per-node fused-GW distance to 10 templates -> linear head.
// Dtype-robust version: a probe kernel inspects input bits to decide
// fp32-vs-bf16 (floats) and int64-vs-int32 (ints) at runtime; all kernels
// branch wave-uniformly on the flags. Output format follows the float flag.
// Numeric fact: K = exp(-G/0.1) underflows (G~30) so y ~= 0; we still compute
// the full FGW faithfully in fp32.

#define NN   20000
#define EE   320000
#define FIN  512
#define HID  64
#define KNEI 8
#define LSZ  9      // K_NEI + 1
#define NTPL 10
#define NTN  8
#define NCLS 6

typedef unsigned short bf16_t;

__device__ __forceinline__ float b2f(bf16_t u) {
  union { unsigned int i; float f; } v; v.i = ((unsigned int)u) << 16; return v.f;
}
__device__ __forceinline__ bf16_t f2b(float f) {
  union { float f; unsigned int i; } v; v.f = f;
  unsigned int x = v.i;
  return (bf16_t)((x + 0x7fffu + ((x >> 16) & 1u)) >> 16);  // RNE
}
__device__ __forceinline__ float ldf(const void* p, long i, int fp32) {
  return fp32 ? ((const float*)p)[i] : b2f(((const bf16_t*)p)[i]);
}
__device__ __forceinline__ int ldi(const void* p, long i, int i64) {
  return i64 ? (int)((const long long*)p)[i] : ((const int*)p)[i];
}

// ---------- dtype probe ----------
// flags[0] = 1 if float tensors are fp32 (else bf16)
// flags[1] = 1 if int tensors are int64 (else int32)
__global__ void probe_kernel(const void* __restrict__ x,
                             const void* __restrict__ ei,
                             int* __restrict__ flags) {
  if (threadIdx.x == 0 && blockIdx.x == 0) {
    // x ~ N(0,1). Decode even-index 16-bit words as bf16; if buffer is really
    // bf16 nearly all have sane exponents; if fp32, even words are mantissa
    // bits -> random exponents (~12% sane).
    int sane = 0;
    for (int k = 0; k < 64; k += 2) {
      bf16_t u = ((const bf16_t*)x)[k];
      int e = (u >> 7) & 0xff;
      if (e >= 112 && e <= 142) sane++;   // |v| in [2^-15, 2^15]
    }
    flags[0] = (sane < 24) ? 1 : 0;
    // edge_index values in [0,20000). If int64, odd 32-bit words (high words)
    // are all zero; if int32 they are uniform node ids (P(0) ~ 5e-5).
    int zc = 0;
    for (int k = 1; k < 64; k += 2)
      if (((const int*)ei)[k] == 0) zc++;
    flags[1] = (zc >= 16) ? 1 : 0;
  }
}

// ---------- degree ----------
__global__ __launch_bounds__(256) void deg_kernel(const void* __restrict__ ei,
                                                  float* __restrict__ deg,
                                                  const int* __restrict__ flags) {
  int i = blockIdx.x * 256 + threadIdx.x;
  int i64 = flags[1];
  if (i < EE) atomicAdd(&deg[ldi(ei, (long)EE + i, i64)], 1.0f);
}
__global__ __launch_bounds__(256) void dinv_kernel(float* __restrict__ deg) {
  int i = blockIdx.x * 256 + threadIdx.x;
  if (i < NN) deg[i] = rsqrtf(deg[i] + 1.0f);   // +1 self loop
}

// ---------- GEMM1: xw1 = x @ W1 ----------
__global__ __launch_bounds__(256) void gemm1_kernel(const void* __restrict__ x,
                                                    const void* __restrict__ W1,
                                                    float* __restrict__ xw1,
                                                    const int* __restrict__ flags) {
  int wave = blockIdx.x * 4 + (threadIdx.x >> 6);
  int lane = threadIdx.x & 63;
  int row0 = wave * 4;                       // NN % 16 == 0
  if (row0 >= NN) return;
  float a0 = 0.f, a1 = 0.f, a2 = 0.f, a3 = 0.f;
  if (flags[0]) {
    const float* x0 = (const float*)x + (long)row0 * FIN;
    const float* wp = (const float*)W1;
#pragma unroll 8
    for (int k = 0; k < FIN; ++k) {
      float w = wp[k * HID + lane];
      a0 += x0[k] * w;
      a1 += x0[FIN + k] * w;
      a2 += x0[2 * FIN + k] * w;
      a3 += x0[3 * FIN + k] * w;
    }
  } else {
    const bf16_t* x0 = (const bf16_t*)x + (long)row0 * FIN;
    const bf16_t* wp = (const bf16_t*)W1;
#pragma unroll 8
    for (int k = 0; k < FIN; ++k) {
      float w = b2f(wp[k * HID + lane]);
      a0 += b2f(x0[k]) * w;
      a1 += b2f(x0[FIN + k]) * w;
      a2 += b2f(x0[2 * FIN + k]) * w;
      a3 += b2f(x0[3 * FIN + k]) * w;
    }
  }
  xw1[(long)(row0 + 0) * HID + lane] = a0;
  xw1[(long)(row0 + 1) * HID + lane] = a1;
  xw1[(long)(row0 + 2) * HID + lane] = a2;
  xw1[(long)(row0 + 3) * HID + lane] = a3;
}

// ---------- GEMM2: xw2 = h1 @ W2 ----------
__global__ __launch_bounds__(256) void gemm2_kernel(const float* __restrict__ h,
                                                    const void* __restrict__ W2,
                                                    float* __restrict__ xw2,
                                                    const int* __restrict__ flags) {
  int wave = blockIdx.x * 4 + (threadIdx.x >> 6);
  int lane = threadIdx.x & 63;
  int row0 = wave * 4;
  if (row0 >= NN) return;
  int fF = flags[0];
  float a0 = 0.f, a1 = 0.f, a2 = 0.f, a3 = 0.f;
  const float* h0 = h + (long)row0 * HID;
#pragma unroll
  for (int k = 0; k < HID; ++k) {
    float w = ldf(W2, k * HID + lane, fF);
    a0 += h0[k] * w;
    a1 += h0[HID + k] * w;
    a2 += h0[2 * HID + k] * w;
    a3 += h0[3 * HID + k] * w;
  }
  xw2[(long)(row0 + 0) * HID + lane] = a0;
  xw2[(long)(row0 + 1) * HID + lane] = a1;
  xw2[(long)(row0 + 2) * HID + lane] = a2;
  xw2[(long)(row0 + 3) * HID + lane] = a3;
}

// ---------- init h with self-loop term ----------
__global__ __launch_bounds__(256) void init_self_kernel(const float* __restrict__ xw,
                                                        const float* __restrict__ dinv,
                                                        float* __restrict__ h) {
  int i = blockIdx.x * 256 + threadIdx.x;  // NN*HID / 256 exact
  int node = i >> 6;
  float dv = dinv[node];
  h[i] = xw[i] * dv * dv;
}

// ---------- edge scatter aggregation ----------
__global__ __launch_bounds__(256) void agg_kernel(const void* __restrict__ ei,
                                                  const float* __restrict__ xw,
                                                  const float* __restrict__ dinv,
                                                  float* __restrict__ h,
                                                  const int* __restrict__ flags) {
  int e = blockIdx.x * 4 + (threadIdx.x >> 6);
  if (e >= EE) return;
  int i64 = flags[1];
  int lane = threadIdx.x & 63;
  int s = ldi(ei, e, i64);
  int d = ldi(ei, (long)EE + e, i64);
  float c = dinv[s] * dinv[d];
  atomicAdd(&h[(long)d * HID + lane], xw[(long)s * HID + lane] * c);
}

// ---------- bias + relu (layer 1) ----------
__global__ __launch_bounds__(256) void bias_relu_kernel(float* __restrict__ h,
                                                        const void* __restrict__ b,
                                                        const int* __restrict__ flags) {
  int i = blockIdx.x * 256 + threadIdx.x;
  float v = h[i] + ldf(b, i & 63, flags[0]);
  h[i] = v > 0.f ? v : 0.f;
}

// ---------- FGW per node + fused final linear ----------
__global__ __launch_bounds__(256) void fgw_kernel(
    const float* __restrict__ h2,        // [NN,64] pre-b2 aggregation (fp32 ws)
    const void* __restrict__ b2v,        // [64]
    const void* __restrict__ nbr_idx,    // [NN,8]
    const void* __restrict__ nbr_mask,   // [NN,9]
    const void* __restrict__ C_local,    // [NN,9,9]
    const void* __restrict__ tmpl,       // [10,8,8]
    const void* __restrict__ tfeat,      // [10,8,64]
    const void* __restrict__ Wlin,       // [74,6]
    const void* __restrict__ blin,       // [6]
    void* __restrict__ out,              // [NN,6]
    const int* __restrict__ flags)
{
  const int n = blockIdx.x;
  const int tid = threadIdx.x;
  const int fF = flags[0];
  const int fI = flags[1];

  __shared__ float xl[LSZ][HID];
  __shared__ float xn2[LSZ], hw[LSZ], f1h1[LSZ];
  __shared__ float C1s[LSZ][LSZ];
  __shared__ float C2s[NTPL][NTN][NTN];
  __shared__ float f2h2[NTPL][NTN];
  __shared__ float Ms[NTPL][72];
  __shared__ float Ts[NTPL][72];
  __shared__ float Ks[NTPL][72];
  __shared__ float As[NTPL][72];
  __shared__ float uu[NTPL][LSZ];
  __shared__ float vv[NTPL][NTN];
  __shared__ float dist[NTPL];
  __shared__ int sidx[LSZ];

  if (tid < LSZ) sidx[tid] = (tid == 0) ? n : ldi(nbr_idx, (long)n * KNEI + tid - 1, fI);
  __syncthreads();

  for (int i = tid; i < LSZ * HID; i += 256) {
    int l = i >> 6, f = i & 63;
    xl[l][f] = h2[(long)sidx[l] * HID + f] + ldf(b2v, f, fF);
  }
  for (int i = tid; i < LSZ * LSZ; i += 256)
    C1s[i / LSZ][i % LSZ] = ldf(C_local, (long)n * (LSZ * LSZ) + i, fF);
  for (int i = tid; i < NTPL * NTN * NTN; i += 256)
    (&C2s[0][0][0])[i] = ldf(tmpl, i, fF);
  if (tid < LSZ) {
    float s = 0.f;
#pragma unroll
    for (int j = 0; j < LSZ; ++j) s += ldf(nbr_mask, (long)n * LSZ + j, fF);
    hw[tid] = ldf(nbr_mask, (long)n * LSZ + tid, fF) / s;
  }
  __syncthreads();

  if (tid < LSZ) {
    float s = 0.f;
#pragma unroll
    for (int k = 0; k < HID; ++k) s += xl[tid][k] * xl[tid][k];
    xn2[tid] = s;
    float g = 0.f;
#pragma unroll
    for (int j = 0; j < LSZ; ++j) g += C1s[tid][j] * C1s[tid][j] * hw[j];
    f1h1[tid] = g;
  }
  if (tid < NTPL * NTN) {
    int t = tid / NTN, m = tid % NTN;
    float s = 0.f;
#pragma unroll
    for (int j = 0; j < NTN; ++j) s += C2s[t][m][j] * C2s[t][m][j];
    f2h2[t][m] = s * 0.125f;
  }
  __syncthreads();

  // cost matrix M[t][l][m]
  if (tid < NTPL * NTN) {
    int t = tid / NTN, m = tid % NTN;
    long tp = (long)(t * NTN + m) * HID;
    float acc[LSZ];
#pragma unroll
    for (int l = 0; l < LSZ; ++l) acc[l] = 0.f;
    float tn2 = 0.f;
    for (int k = 0; k < HID; ++k) {
      float tv = ldf(tfeat, tp + k, fF);
      tn2 += tv * tv;
#pragma unroll
      for (int l = 0; l < LSZ; ++l) acc[l] += xl[l][k] * tv;
    }
#pragma unroll
    for (int l = 0; l < LSZ; ++l)
      Ms[t][l * NTN + m] = xn2[l] + tn2 - 2.f * acc[l];
  }
  // T0
  for (int i = tid; i < NTPL * 72; i += 256) {
    int t = i / 72, e = i % 72;
    Ts[t][e] = hw[e >> 3] * 0.125f;
  }
  __syncthreads();

  for (int outer = 0; outer < 3; ++outer) {
    for (int i = tid; i < NTPL * 72; i += 256) {   // A = C1 @ T
      int t = i / 72, e = i % 72, m = e & 7;
      float s = 0.f;
#pragma unroll
      for (int j = 0; j < LSZ; ++j) s += C1s[e >> 3][j] * Ts[t][j * NTN + m];
      As[t][e] = s;
    }
    __syncthreads();
    for (int i = tid; i < NTPL * 72; i += 256) {   // K = exp(-G/eps)
      int t = i / 72, e = i % 72, l = e >> 3, m = e & 7;
      float s = 0.f;
#pragma unroll
      for (int j = 0; j < NTN; ++j) s += As[t][l * NTN + j] * C2s[t][j][m];
      float tens = f1h1[l] + f2h2[t][m] - 2.f * s;
      Ks[t][e] = __expf(-10.0f * (0.5f * Ms[t][e] + 0.5f * tens));
    }
    if (tid < NTPL * NTN) vv[tid / NTN][tid % NTN] = 1.0f;
    __syncthreads();
    for (int it = 0; it < 5; ++it) {
      if (tid < NTPL * LSZ) {
        int t = tid / LSZ, l = tid % LSZ;
        float s = 0.f;
#pragma unroll
        for (int m = 0; m < NTN; ++m) s += Ks[t][l * NTN + m] * vv[t][m];
        uu[t][l] = hw[l] / (s + 1e-16f);
      }
      __syncthreads();
      if (tid < NTPL * NTN) {
        int t = tid / NTN, m = tid % NTN;
        float s = 0.f;
#pragma unroll
        for (int l = 0; l < LSZ; ++l) s += Ks[t][l * NTN + m] * uu[t][l];
        vv[t][m] = 0.125f / (s + 1e-16f);
      }
      __syncthreads();
    }
    for (int i = tid; i < NTPL * 72; i += 256) {   // T = u*K*v
      int t = i / 72, e = i % 72, l = e >> 3, m = e & 7;
      Ts[t][e] = uu[t][l] * Ks[t][e] * vv[t][m];
    }
    __syncthreads();
  }

  // dist[t] = sum T * (0.5*M + 0.5*tens(T))
  for (int i = tid; i < NTPL * 72; i += 256) {
    int t = i / 72, e = i % 72, m = e & 7;
    float s = 0.f;
#pragma unroll
    for (int j = 0; j < LSZ; ++j) s += C1s[e >> 3][j] * Ts[t][j * NTN + m];
    As[t][e] = s;
  }
  __syncthreads();
  for (int i = tid; i < NTPL * 72; i += 256) {
    int t = i / 72, e = i % 72, l = e >> 3, m = e & 7;
    float s = 0.f;
#pragma unroll
    for (int j = 0; j < NTN; ++j) s += As[t][l * NTN + j] * C2s[t][j][m];
    float tens = f1h1[l] + f2h2[t][m] - 2.f * s;
    Ks[t][e] = Ts[t][e] * (0.5f * Ms[t][e] + 0.5f * tens);
  }
  __syncthreads();
  if (tid < NTPL) {
    float s = 0.f;
    for (int e = 0; e < 72; ++e) s += Ks[tid][e];
    dist[tid] = s;
  }
  __syncthreads();

  // epilogue: out = relu([h, y] @ Wlin + blin)
  if (tid < NCLS) {
    float acc = ldf(blin, tid, fF);
#pragma unroll
    for (int j = 0; j < HID; ++j) acc += xl[0][j] * ldf(Wlin, j * NCLS + tid, fF);
#pragma unroll
    for (int t = 0; t < NTPL; ++t) acc += dist[t] * ldf(Wlin, (HID + t) * NCLS + tid, fF);
    float r = acc > 0.f ? acc : 0.f;
    if (fF) ((float*)out)[(long)n * NCLS + tid] = r;
    else    ((bf16_t*)out)[(long)n * NCLS + tid] = f2b(r);
  }
}

extern "C" void kernel_launch(void* const* d_in, const int* in_sizes, int n_in,
                              void* d_out, int out_size, void* d_ws, size_t ws_size,
                              hipStream_t stream) {
  (void)in_sizes; (void)n_in; (void)out_size; (void)ws_size;
  const void* x     = d_in[0];
  const void* ei    = d_in[1];
  const void* nbr   = d_in[2];
  const void* nmask = d_in[3];
  const void* Cl    = d_in[4];
  const void* W1    = d_in[5];
  const void* b1    = d_in[6];
  const void* W2    = d_in[7];
  const void* b2    = d_in[8];
  const void* tmpl  = d_in[9];
  const void* tfeat = d_in[10];
  const void* Wlin  = d_in[11];
  const void* blin  = d_in[12];

  // workspace: [flags(16 ints pad)] [dinv NN] [bufA NN*HID] [bufB NN*HID]
  int*   flags = (int*)d_ws;
  float* dinv  = (float*)d_ws + 16;
  float* bufA  = dinv + NN;
  float* bufB  = bufA + (long)NN * HID;

  probe_kernel<<<1, 64, 0, stream>>>(x, ei, flags);

  hipMemsetAsync(dinv, 0, NN * sizeof(float), stream);
  deg_kernel<<<(EE + 255) / 256, 256, 0, stream>>>(ei, dinv, flags);
  dinv_kernel<<<(NN + 255) / 256, 256, 0, stream>>>(dinv);

  // layer 1: xw1 -> bufA, h1 -> bufB
  gemm1_kernel<<<NN / 16, 256, 0, stream>>>(x, W1, bufA, flags);
  init_self_kernel<<<NN * HID / 256, 256, 0, stream>>>(bufA, dinv, bufB);
  agg_kernel<<<EE / 4, 256, 0, stream>>>(ei, bufA, dinv, bufB, flags);
  bias_relu_kernel<<<NN * HID / 256, 256, 0, stream>>>(bufB, b1, flags);

  // layer 2: xw2 -> bufA (h1=bufB dead after gemm2), h2 -> bufB
  gemm2_kernel<<<NN / 16, 256, 0, stream>>>(bufB, W2, bufA, flags);
  init_self_kernel<<<NN * HID / 256, 256, 0, stream>>>(bufA, dinv, bufB);
  agg_kernel<<<EE / 4, 256, 0, stream>>>(ei, bufA, dinv, bufB, flags);

  fgw_kernel<<<NN, 256, 0, stream>>>(bufB, b2, nbr, nmask, Cl, tmpl, tfeat,
                                     Wlin, blin, d_out, flags);
}

// Round 3
// 981.369 us; speedup vs baseline: 1.0822x; 1.0822x over previous
//
#include <hip/hip_runtime.h>

// OT_GNN: 2x GCN -> per-node fused-GW distance to 10 templates -> linear head.
// R3: FGW restructured as one 8-lane octet per (node,template), register-
// resident sinkhorn with intra-octet shuffles, zero barriers in the iteration.
// Dtype probe (fp32-vs-bf16 floats, int64-vs-int32 ints) retained from R2.

#define NN   20000
#define EE   320000
#define FIN  512
#define HID  64
#define KNEI 8
#define LSZ  9      // K_NEI + 1
#define NTPL 10
#define NTN  8
#define NCLS 6

typedef unsigned short bf16_t;

__device__ __forceinline__ float b2f(bf16_t u) {
  union { unsigned int i; float f; } v; v.i = ((unsigned int)u) << 16; return v.f;
}
__device__ __forceinline__ bf16_t f2b(float f) {
  union { float f; unsigned int i; } v; v.f = f;
  unsigned int x = v.i;
  return (bf16_t)((x + 0x7fffu + ((x >> 16) & 1u)) >> 16);  // RNE
}
__device__ __forceinline__ float ldf(const void* p, long i, int fp32) {
  return fp32 ? ((const float*)p)[i] : b2f(((const bf16_t*)p)[i]);
}
__device__ __forceinline__ int ldi(const void* p, long i, int i64) {
  return i64 ? (int)((const long long*)p)[i] : ((const int*)p)[i];
}
__device__ __forceinline__ float frcp(float x) { return __builtin_amdgcn_rcpf(x); }

// ---------- dtype probe ----------
__global__ void probe_kernel(const void* __restrict__ x,
                             const void* __restrict__ ei,
                             int* __restrict__ flags) {
  if (threadIdx.x == 0 && blockIdx.x == 0) {
    int sane = 0;
    for (int k = 0; k < 64; k += 2) {
      bf16_t u = ((const bf16_t*)x)[k];
      int e = (u >> 7) & 0xff;
      if (e >= 112 && e <= 142) sane++;
    }
    flags[0] = (sane < 24) ? 1 : 0;
    int zc = 0;
    for (int k = 1; k < 64; k += 2)
      if (((const int*)ei)[k] == 0) zc++;
    flags[1] = (zc >= 16) ? 1 : 0;
  }
}

// ---------- degree ----------
__global__ __launch_bounds__(256) void deg_kernel(const void* __restrict__ ei,
                                                  float* __restrict__ deg,
                                                  const int* __restrict__ flags) {
  int i = blockIdx.x * 256 + threadIdx.x;
  int i64 = flags[1];
  if (i < EE) atomicAdd(&deg[ldi(ei, (long)EE + i, i64)], 1.0f);
}
__global__ __launch_bounds__(256) void dinv_kernel(float* __restrict__ deg) {
  int i = blockIdx.x * 256 + threadIdx.x;
  if (i < NN) deg[i] = rsqrtf(deg[i] + 1.0f);
}

// ---------- GEMM1: xw1 = x @ W1 ----------
__global__ __launch_bounds__(256) void gemm1_kernel(const void* __restrict__ x,
                                                    const void* __restrict__ W1,
                                                    float* __restrict__ xw1,
                                                    const int* __restrict__ flags) {
  int wave = blockIdx.x * 4 + (threadIdx.x >> 6);
  int lane = threadIdx.x & 63;
  int row0 = wave * 4;
  if (row0 >= NN) return;
  float a0 = 0.f, a1 = 0.f, a2 = 0.f, a3 = 0.f;
  if (flags[0]) {
    const float* x0 = (const float*)x + (long)row0 * FIN;
    const float* wp = (const float*)W1;
#pragma unroll 8
    for (int k = 0; k < FIN; ++k) {
      float w = wp[k * HID + lane];
      a0 += x0[k] * w;
      a1 += x0[FIN + k] * w;
      a2 += x0[2 * FIN + k] * w;
      a3 += x0[3 * FIN + k] * w;
    }
  } else {
    const bf16_t* x0 = (const bf16_t*)x + (long)row0 * FIN;
    const bf16_t* wp = (const bf16_t*)W1;
#pragma unroll 8
    for (int k = 0; k < FIN; ++k) {
      float w = b2f(wp[k * HID + lane]);
      a0 += b2f(x0[k]) * w;
      a1 += b2f(x0[FIN + k]) * w;
      a2 += b2f(x0[2 * FIN + k]) * w;
      a3 += b2f(x0[3 * FIN + k]) * w;
    }
  }
  xw1[(long)(row0 + 0) * HID + lane] = a0;
  xw1[(long)(row0 + 1) * HID + lane] = a1;
  xw1[(long)(row0 + 2) * HID + lane] = a2;
  xw1[(long)(row0 + 3) * HID + lane] = a3;
}

// ---------- GEMM2: xw2 = h1 @ W2 ----------
__global__ __launch_bounds__(256) void gemm2_kernel(const float* __restrict__ h,
                                                    const void* __restrict__ W2,
                                                    float* __restrict__ xw2,
                                                    const int* __restrict__ flags) {
  int wave = blockIdx.x * 4 + (threadIdx.x >> 6);
  int lane = threadIdx.x & 63;
  int row0 = wave * 4;
  if (row0 >= NN) return;
  int fF = flags[0];
  float a0 = 0.f, a1 = 0.f, a2 = 0.f, a3 = 0.f;
  const float* h0 = h + (long)row0 * HID;
#pragma unroll
  for (int k = 0; k < HID; ++k) {
    float w = ldf(W2, k * HID + lane, fF);
    a0 += h0[k] * w;
    a1 += h0[HID + k] * w;
    a2 += h0[2 * HID + k] * w;
    a3 += h0[3 * HID + k] * w;
  }
  xw2[(long)(row0 + 0) * HID + lane] = a0;
  xw2[(long)(row0 + 1) * HID + lane] = a1;
  xw2[(long)(row0 + 2) * HID + lane] = a2;
  xw2[(long)(row0 + 3) * HID + lane] = a3;
}

// ---------- init h with self-loop term ----------
__global__ __launch_bounds__(256) void init_self_kernel(const float* __restrict__ xw,
                                                        const float* __restrict__ dinv,
                                                        float* __restrict__ h) {
  int i = blockIdx.x * 256 + threadIdx.x;
  int node = i >> 6;
  float dv = dinv[node];
  h[i] = xw[i] * dv * dv;
}

// ---------- edge scatter aggregation ----------
__global__ __launch_bounds__(256) void agg_kernel(const void* __restrict__ ei,
                                                  const float* __restrict__ xw,
                                                  const float* __restrict__ dinv,
                                                  float* __restrict__ h,
                                                  const int* __restrict__ flags) {
  int e = blockIdx.x * 4 + (threadIdx.x >> 6);
  if (e >= EE) return;
  int i64 = flags[1];
  int lane = threadIdx.x & 63;
  int s = ldi(ei, e, i64);
  int d = ldi(ei, (long)EE + e, i64);
  float c = dinv[s] * dinv[d];
  atomicAdd(&h[(long)d * HID + lane], xw[(long)s * HID + lane] * c);
}

// ---------- bias + relu (layer 1) ----------
__global__ __launch_bounds__(256) void bias_relu_kernel(float* __restrict__ h,
                                                        const void* __restrict__ b,
                                                        const int* __restrict__ flags) {
  int i = blockIdx.x * 256 + threadIdx.x;
  float v = h[i] + ldf(b, i & 63, flags[0]);
  h[i] = v > 0.f ? v : 0.f;
}

// ---------- FGW: 4 nodes/block, 8-lane octet per (node, template) ----------
#define NODES_PB 4
#define TPN 80            // threads per node (10 templates x 8 lanes)
#define XLP 65            // padded xl row stride

__global__ __launch_bounds__(320, 2) void fgw_kernel(
    const float* __restrict__ h2,        // [NN,64] fp32 ws (pre-b2)
    const void* __restrict__ b2v,
    const void* __restrict__ nbr_idx,
    const void* __restrict__ nbr_mask,
    const void* __restrict__ C_local,
    const void* __restrict__ tmpl,       // [10,8,8]
    const void* __restrict__ tfeat,      // [10,8,64]
    const void* __restrict__ Wlin,       // [74,6]
    const void* __restrict__ blin,       // [6]
    void* __restrict__ out,              // [NN,6]
    const int* __restrict__ flags)
{
  const int tid = threadIdx.x;
  const int fF = flags[0];
  const int fI = flags[1];
  const int nb = tid / TPN;              // node slot in block [0,4)
  const int local = tid - nb * TPN;      // [0,80)
  const int t = local >> 3;              // template [0,10)
  const int j = local & 7;               // column m owned by this lane
  const int n = blockIdx.x * NODES_PB + nb;
  const int lane = tid & 63;
  const int ob = lane & 56;              // octet base within wave

  __shared__ float xlS[NODES_PB][LSZ][XLP];
  __shared__ float C1S[NODES_PB][81];
  __shared__ float hwS[NODES_PB][LSZ];
  __shared__ float f1S[NODES_PB][LSZ];
  __shared__ float xnS[NODES_PB][LSZ];
  __shared__ float distS[NODES_PB][NTPL];
  __shared__ int   sidxS[NODES_PB][LSZ];

  // phase 1: neighbor indices
  if (local < LSZ)
    sidxS[nb][local] = (local == 0) ? n : ldi(nbr_idx, (long)n * KNEI + local - 1, fI);
  __syncthreads();

  // phase 2: stage xl (+b2) and C1
  for (int i = local; i < LSZ * HID; i += TPN) {
    int l = i >> 6, k = i & 63;
    xlS[nb][l][k] = h2[(long)sidxS[nb][l] * HID + k] + ldf(b2v, k, fF);
  }
  for (int i = local; i < 81; i += TPN)
    C1S[nb][i] = ldf(C_local, (long)n * 81 + i, fF);

  // thread-local template data (no deps on LDS)
  float C2c[NTN];          // C2[t][m][j], column j
  float f2h2;              // (C2[t]^2 @ h2)[j], needs row j
  {
    float s = 0.f;
#pragma unroll
    for (int m = 0; m < NTN; ++m) {
      C2c[m] = ldf(tmpl, t * 64 + m * 8 + j, fF);
      float r = ldf(tmpl, t * 64 + j * 8 + m, fF);
      s += r * r;
    }
    f2h2 = s * 0.125f;
  }
  __syncthreads();

  // phase 3: per-node vectors (9 threads per node)
  if (local < LSZ) {
    int l = local;
    float msum = 0.f, f1 = 0.f;
#pragma unroll
    for (int jj = 0; jj < LSZ; ++jj) {
      float mj = ldf(nbr_mask, (long)n * LSZ + jj, fF);
      msum += mj;
      float c = C1S[nb][l * LSZ + jj];
      f1 += c * c * mj;
    }
    float inv = frcp(msum);
    hwS[nb][l] = ldf(nbr_mask, (long)n * LSZ + l, fF) * inv;
    f1S[nb][l] = f1 * inv;
    float s = 0.f;
#pragma unroll
    for (int k = 0; k < HID; ++k) {
      float v = xlS[nb][l][k];
      s += v * v;
    }
    xnS[nb][l] = s;
  }
  __syncthreads();

  // phase 4: register-resident FGW (no barriers)
  float hwr[LSZ], f1r[LSZ];
#pragma unroll
  for (int l = 0; l < LSZ; ++l) { hwr[l] = hwS[nb][l]; f1r[l] = f1S[nb][l]; }

  // cost matrix column j of template t: Mc[l]
  float Mc[LSZ];
  {
    float accI[LSZ];
#pragma unroll
    for (int l = 0; l < LSZ; ++l) accI[l] = 0.f;
    float tn2 = 0.f;
    const long tb = (long)local * HID;   // row (t*8+j) of tfeat
    for (int kb = 0; kb < 8; ++kb) {
      float r[8];
#pragma unroll
      for (int q = 0; q < 8; ++q) r[q] = ldf(tfeat, tb + kb * 8 + q, fF);
#pragma unroll
      for (int q = 0; q < 8; ++q) tn2 += r[q] * r[q];
#pragma unroll
      for (int l = 0; l < LSZ; ++l) {
        float s = 0.f;
#pragma unroll
        for (int q = 0; q < 8; ++q) s += xlS[nb][l][kb * 8 + q] * r[q];
        accI[l] += s;
      }
    }
#pragma unroll
    for (int l = 0; l < LSZ; ++l)
      Mc[l] = xnS[nb][l] + tn2 - 2.f * accI[l];
  }

  float Tc[LSZ], Kc[LSZ], u[LSZ];
#pragma unroll
  for (int l = 0; l < LSZ; ++l) Tc[l] = hwr[l] * 0.125f;   // T0

  float v = 1.0f;
  for (int outer = 0; outer < 3; ++outer) {
    // A = C1 @ T (column j), then K = exp(-10*(0.5*M + 0.5*tens))
    float Ac[LSZ];
#pragma unroll
    for (int l = 0; l < LSZ; ++l) {
      float s = 0.f;
#pragma unroll
      for (int l2 = 0; l2 < LSZ; ++l2) s += C1S[nb][l * LSZ + l2] * Tc[l2];
      Ac[l] = s;
    }
#pragma unroll
    for (int l = 0; l < LSZ; ++l) {
      float s = 0.f;
#pragma unroll
      for (int m = 0; m < NTN; ++m) s += __shfl(Ac[l], ob + m) * C2c[m];
      float tens = f1r[l] + f2h2 - 2.f * s;
      Kc[l] = __expf(-5.0f * (Mc[l] + tens));   // -10*0.5*(M+tens)
    }
    v = 1.0f;
    // 5 sinkhorn iterations, all intra-octet
    for (int it = 0; it < 5; ++it) {
#pragma unroll
      for (int l = 0; l < LSZ; ++l) {
        float p = Kc[l] * v;
        p += __shfl_xor(p, 1); p += __shfl_xor(p, 2); p += __shfl_xor(p, 4);
        u[l] = hwr[l] * frcp(p + 1e-16f);
      }
      float s = 0.f;
#pragma unroll
      for (int l = 0; l < LSZ; ++l) s += Kc[l] * u[l];
      v = 0.125f * frcp(s + 1e-16f);
    }
#pragma unroll
    for (int l = 0; l < LSZ; ++l) Tc[l] = u[l] * Kc[l] * v;
  }

  // final distance: sum T * (0.5*M + 0.5*tens(T))
  {
    float Ac[LSZ];
#pragma unroll
    for (int l = 0; l < LSZ; ++l) {
      float s = 0.f;
#pragma unroll
      for (int l2 = 0; l2 < LSZ; ++l2) s += C1S[nb][l * LSZ + l2] * Tc[l2];
      Ac[l] = s;
    }
    float cl = 0.f;
#pragma unroll
    for (int l = 0; l < LSZ; ++l) {
      float s = 0.f;
#pragma unroll
      for (int m = 0; m < NTN; ++m) s += __shfl(Ac[l], ob + m) * C2c[m];
      float tens = f1r[l] + f2h2 - 2.f * s;
      cl += Tc[l] * 0.5f * (Mc[l] + tens);
    }
    cl += __shfl_xor(cl, 1); cl += __shfl_xor(cl, 2); cl += __shfl_xor(cl, 4);
    if (j == 0) distS[nb][t] = cl;
  }
  __syncthreads();

  // epilogue: out[n] = relu([xl0, dist] @ Wlin + blin)
  if (local < NCLS) {
    int c = local;
    float acc = ldf(blin, c, fF);
#pragma unroll
    for (int k = 0; k < HID; ++k)
      acc += xlS[nb][0][k] * ldf(Wlin, k * NCLS + c, fF);
#pragma unroll
    for (int tt = 0; tt < NTPL; ++tt)
      acc += distS[nb][tt] * ldf(Wlin, (HID + tt) * NCLS + c, fF);
    float r = acc > 0.f ? acc : 0.f;
    if (fF) ((float*)out)[(long)n * NCLS + c] = r;
    else    ((bf16_t*)out)[(long)n * NCLS + c] = f2b(r);
  }
}

extern "C" void kernel_launch(void* const* d_in, const int* in_sizes, int n_in,
                              void* d_out, int out_size, void* d_ws, size_t ws_size,
                              hipStream_t stream) {
  (void)in_sizes; (void)n_in; (void)out_size; (void)ws_size;
  const void* x     = d_in[0];
  const void* ei    = d_in[1];
  const void* nbr   = d_in[2];
  const void* nmask = d_in[3];
  const void* Cl    = d_in[4];
  const void* W1    = d_in[5];
  const void* b1    = d_in[6];
  const void* W2    = d_in[7];
  const void* b2    = d_in[8];
  const void* tmpl  = d_in[9];
  const void* tfeat = d_in[10];
  const void* Wlin  = d_in[11];
  const void* blin  = d_in[12];

  int*   flags = (int*)d_ws;
  float* dinv  = (float*)d_ws + 16;
  float* bufA  = dinv + NN;
  float* bufB  = bufA + (long)NN * HID;

  probe_kernel<<<1, 64, 0, stream>>>(x, ei, flags);

  hipMemsetAsync(dinv, 0, NN * sizeof(float), stream);
  deg_kernel<<<(EE + 255) / 256, 256, 0, stream>>>(ei, dinv, flags);
  dinv_kernel<<<(NN + 255) / 256, 256, 0, stream>>>(dinv);

  gemm1_kernel<<<NN / 16, 256, 0, stream>>>(x, W1, bufA, flags);
  init_self_kernel<<<NN * HID / 256, 256, 0, stream>>>(bufA, dinv, bufB);
  agg_kernel<<<EE / 4, 256, 0, stream>>>(ei, bufA, dinv, bufB, flags);
  bias_relu_kernel<<<NN * HID / 256, 256, 0, stream>>>(bufB, b1, flags);

  gemm2_kernel<<<NN / 16, 256, 0, stream>>>(bufB, W2, bufA, flags);
  init_self_kernel<<<NN * HID / 256, 256, 0, stream>>>(bufA, dinv, bufB);
  agg_kernel<<<EE / 4, 256, 0, stream>>>(ei, bufA, dinv, bufB, flags);

  fgw_kernel<<<NN / NODES_PB, 320, 0, stream>>>(bufB, b2, nbr, nmask, Cl, tmpl,
                                                tfeat, Wlin, blin, d_out, flags);
}

// Round 4
// 506.195 us; speedup vs baseline: 2.0980x; 1.9387x over previous
//
#include <hip/hip_runtime.h>

// OT_GNN: 2x GCN -> per-node fused-GW distance to 10 templates -> linear head.
// R4: provable fast path. K = exp(-G/0.1) is EXACTLY 0 in fp32 whenever
// min M > 22.8 (tens >= -2 bound from C1 in {0,1}, C2 in [0,1], sum T <= 1),
// which makes T == 0 and dist == 0 bit-exactly per reference semantics.
// Cauchy-Schwarz certificate: M[l][m] >= (sqrt(tn2[m]) - sqrt(xn2[l]))^2.
// Octets satisfying the certificate skip the whole FGW; others run the
// faithful R3 register-resident fallback.

#define NN   20000
#define EE   320000
#define FIN  512
#define HID  64
#define KNEI 8
#define LSZ  9      // K_NEI + 1
#define NTPL 10
#define NTN  8
#define NCLS 6

typedef unsigned short bf16_t;

__device__ __forceinline__ float b2f(bf16_t u) {
  union { unsigned int i; float f; } v; v.i = ((unsigned int)u) << 16; return v.f;
}
__device__ __forceinline__ bf16_t f2b(float f) {
  union { float f; unsigned int i; } v; v.f = f;
  unsigned int x = v.i;
  return (bf16_t)((x + 0x7fffu + ((x >> 16) & 1u)) >> 16);  // RNE
}
__device__ __forceinline__ float ldf(const void* p, long i, int fp32) {
  return fp32 ? ((const float*)p)[i] : b2f(((const bf16_t*)p)[i]);
}
__device__ __forceinline__ int ldi(const void* p, long i, int i64) {
  return i64 ? (int)((const long long*)p)[i] : ((const int*)p)[i];
}
__device__ __forceinline__ float frcp(float x) { return __builtin_amdgcn_rcpf(x); }

// ---------- dtype probe + template row-norm mins ----------
__global__ __launch_bounds__(128) void probe_kernel(const void* __restrict__ x,
                                                    const void* __restrict__ ei,
                                                    const void* __restrict__ tfeat,
                                                    int* __restrict__ flags,
                                                    float* __restrict__ tn2min) {
  __shared__ int sfl[2];
  __shared__ float tn2s[80];
  int tid = threadIdx.x;
  if (tid == 0) {
    int sane = 0;
    for (int k = 0; k < 64; k += 2) {
      bf16_t u = ((const bf16_t*)x)[k];
      int e = (u >> 7) & 0xff;
      if (e >= 112 && e <= 142) sane++;
    }
    int f0 = (sane < 24) ? 1 : 0;
    int zc = 0;
    for (int k = 1; k < 64; k += 2)
      if (((const int*)ei)[k] == 0) zc++;
    int f1 = (zc >= 16) ? 1 : 0;
    flags[0] = f0; flags[1] = f1;
    sfl[0] = f0; sfl[1] = f1;
  }
  __syncthreads();
  if (tid < 80) {
    int fF = sfl[0];
    float s = 0.f;
    for (int k = 0; k < HID; ++k) {
      float v = ldf(tfeat, (long)tid * HID + k, fF);
      s += v * v;
    }
    tn2s[tid] = s;
  }
  __syncthreads();
  if (tid < NTPL) {
    float m = tn2s[tid * 8];
    for (int r = 1; r < 8; ++r) m = fminf(m, tn2s[tid * 8 + r]);
    tn2min[tid] = m;
  }
}

// ---------- degree ----------
__global__ __launch_bounds__(256) void deg_kernel(const void* __restrict__ ei,
                                                  float* __restrict__ deg,
                                                  const int* __restrict__ flags) {
  int i = blockIdx.x * 256 + threadIdx.x;
  int i64 = flags[1];
  if (i < EE) atomicAdd(&deg[ldi(ei, (long)EE + i, i64)], 1.0f);
}
__global__ __launch_bounds__(256) void dinv_kernel(float* __restrict__ deg) {
  int i = blockIdx.x * 256 + threadIdx.x;
  if (i < NN) deg[i] = rsqrtf(deg[i] + 1.0f);
}

// ---------- GEMM1: xw1 = x @ W1 ----------
__global__ __launch_bounds__(256) void gemm1_kernel(const void* __restrict__ x,
                                                    const void* __restrict__ W1,
                                                    float* __restrict__ xw1,
                                                    const int* __restrict__ flags) {
  int wave = blockIdx.x * 4 + (threadIdx.x >> 6);
  int lane = threadIdx.x & 63;
  int row0 = wave * 4;
  if (row0 >= NN) return;
  float a0 = 0.f, a1 = 0.f, a2 = 0.f, a3 = 0.f;
  if (flags[0]) {
    const float* x0 = (const float*)x + (long)row0 * FIN;
    const float* wp = (const float*)W1;
#pragma unroll 8
    for (int k = 0; k < FIN; ++k) {
      float w = wp[k * HID + lane];
      a0 += x0[k] * w;
      a1 += x0[FIN + k] * w;
      a2 += x0[2 * FIN + k] * w;
      a3 += x0[3 * FIN + k] * w;
    }
  } else {
    const bf16_t* x0 = (const bf16_t*)x + (long)row0 * FIN;
    const bf16_t* wp = (const bf16_t*)W1;
#pragma unroll 8
    for (int k = 0; k < FIN; ++k) {
      float w = b2f(wp[k * HID + lane]);
      a0 += b2f(x0[k]) * w;
      a1 += b2f(x0[FIN + k]) * w;
      a2 += b2f(x0[2 * FIN + k]) * w;
      a3 += b2f(x0[3 * FIN + k]) * w;
    }
  }
  xw1[(long)(row0 + 0) * HID + lane] = a0;
  xw1[(long)(row0 + 1) * HID + lane] = a1;
  xw1[(long)(row0 + 2) * HID + lane] = a2;
  xw1[(long)(row0 + 3) * HID + lane] = a3;
}

// ---------- GEMM2: xw2 = h1 @ W2 ----------
__global__ __launch_bounds__(256) void gemm2_kernel(const float* __restrict__ h,
                                                    const void* __restrict__ W2,
                                                    float* __restrict__ xw2,
                                                    const int* __restrict__ flags) {
  int wave = blockIdx.x * 4 + (threadIdx.x >> 6);
  int lane = threadIdx.x & 63;
  int row0 = wave * 4;
  if (row0 >= NN) return;
  int fF = flags[0];
  float a0 = 0.f, a1 = 0.f, a2 = 0.f, a3 = 0.f;
  const float* h0 = h + (long)row0 * HID;
#pragma unroll
  for (int k = 0; k < HID; ++k) {
    float w = ldf(W2, k * HID + lane, fF);
    a0 += h0[k] * w;
    a1 += h0[HID + k] * w;
    a2 += h0[2 * HID + k] * w;
    a3 += h0[3 * HID + k] * w;
  }
  xw2[(long)(row0 + 0) * HID + lane] = a0;
  xw2[(long)(row0 + 1) * HID + lane] = a1;
  xw2[(long)(row0 + 2) * HID + lane] = a2;
  xw2[(long)(row0 + 3) * HID + lane] = a3;
}

// ---------- init h with self-loop term ----------
__global__ __launch_bounds__(256) void init_self_kernel(const float* __restrict__ xw,
                                                        const float* __restrict__ dinv,
                                                        float* __restrict__ h) {
  int i = blockIdx.x * 256 + threadIdx.x;
  int node = i >> 6;
  float dv = dinv[node];
  h[i] = xw[i] * dv * dv;
}

// ---------- edge scatter aggregation ----------
__global__ __launch_bounds__(256) void agg_kernel(const void* __restrict__ ei,
                                                  const float* __restrict__ xw,
                                                  const float* __restrict__ dinv,
                                                  float* __restrict__ h,
                                                  const int* __restrict__ flags) {
  int e = blockIdx.x * 4 + (threadIdx.x >> 6);
  if (e >= EE) return;
  int i64 = flags[1];
  int lane = threadIdx.x & 63;
  int s = ldi(ei, e, i64);
  int d = ldi(ei, (long)EE + e, i64);
  float c = dinv[s] * dinv[d];
  atomicAdd(&h[(long)d * HID + lane], xw[(long)s * HID + lane] * c);
}

// ---------- bias + relu (layer 1) ----------
__global__ __launch_bounds__(256) void bias_relu_kernel(float* __restrict__ h,
                                                        const void* __restrict__ b,
                                                        const int* __restrict__ flags) {
  int i = blockIdx.x * 256 + threadIdx.x;
  float v = h[i] + ldf(b, i & 63, flags[0]);
  h[i] = v > 0.f ? v : 0.f;
}

// ---------- FGW: 4 nodes/block, 8-lane octet per (node, template) ----------
#define NODES_PB 4
#define TPN 80            // threads per node (10 templates x 8 lanes)
#define XLP 65            // padded xl row stride

__global__ __launch_bounds__(320, 2) void fgw_kernel(
    const float* __restrict__ h2,        // [NN,64] fp32 ws (pre-b2)
    const void* __restrict__ b2v,
    const void* __restrict__ nbr_idx,
    const void* __restrict__ nbr_mask,
    const void* __restrict__ C_local,
    const void* __restrict__ tmpl,       // [10,8,8]
    const void* __restrict__ tfeat,      // [10,8,64]
    const void* __restrict__ Wlin,       // [74,6]
    const void* __restrict__ blin,       // [6]
    void* __restrict__ out,              // [NN,6]
    const int* __restrict__ flags,
    const float* __restrict__ tn2min)    // [10] min template row-norm^2
{
  const int tid = threadIdx.x;
  const int fF = flags[0];
  const int fI = flags[1];
  const int nb = tid / TPN;              // node slot in block [0,4)
  const int local = tid - nb * TPN;      // [0,80)
  const int t = local >> 3;              // template [0,10)
  const int j = local & 7;               // column m owned by this lane
  const int n = blockIdx.x * NODES_PB + nb;
  const int lane = tid & 63;
  const int ob = lane & 56;              // octet base within wave

  __shared__ float xlS[NODES_PB][LSZ][XLP];
  __shared__ float C1S[NODES_PB][81];
  __shared__ float hwS[NODES_PB][LSZ];
  __shared__ float f1S[NODES_PB][LSZ];
  __shared__ float xnS[NODES_PB][LSZ];
  __shared__ float distS[NODES_PB][NTPL];
  __shared__ int   sidxS[NODES_PB][LSZ];

  // phase 1: neighbor indices
  if (local < LSZ)
    sidxS[nb][local] = (local == 0) ? n : ldi(nbr_idx, (long)n * KNEI + local - 1, fI);
  __syncthreads();

  // phase 2: stage xl (+b2) and C1
  for (int i = local; i < LSZ * HID; i += TPN) {
    int l = i >> 6, k = i & 63;
    xlS[nb][l][k] = h2[(long)sidxS[nb][l] * HID + k] + ldf(b2v, k, fF);
  }
  for (int i = local; i < 81; i += TPN)
    C1S[nb][i] = ldf(C_local, (long)n * 81 + i, fF);
  __syncthreads();

  // phase 3: per-node vectors (9 threads per node)
  if (local < LSZ) {
    int l = local;
    float msum = 0.f, f1 = 0.f;
#pragma unroll
    for (int jj = 0; jj < LSZ; ++jj) {
      float mj = ldf(nbr_mask, (long)n * LSZ + jj, fF);
      msum += mj;
      float c = C1S[nb][l * LSZ + jj];
      f1 += c * c * mj;
    }
    float inv = frcp(msum);
    hwS[nb][l] = ldf(nbr_mask, (long)n * LSZ + l, fF) * inv;
    f1S[nb][l] = f1 * inv;
    float s = 0.f;
#pragma unroll
    for (int k = 0; k < HID; ++k) {
      float v = xlS[nb][l][k];
      s += v * v;
    }
    xnS[nb][l] = s;
  }
  __syncthreads();

  // ---- fast-path certificate (octet-uniform) ----
  // M[l][m] >= (sqrt(tn2[m]) - sqrt(xn2[l]))^2 and tens >= -2, so
  // gap >= sqrt(26) => exp arg < -120 < -104 => K == 0 => dist == 0 exactly.
  float xmax = xnS[nb][0];
#pragma unroll
  for (int l = 1; l < LSZ; ++l) xmax = fmaxf(xmax, xnS[nb][l]);
  bool fast = (sqrtf(tn2min[t]) - sqrtf(xmax)) >= 5.0990195f;

  if (!fast) {
    // ---------- faithful R3 fallback ----------
    float C2c[NTN];
    float f2h2;
    {
      float s = 0.f;
#pragma unroll
      for (int m = 0; m < NTN; ++m) {
        C2c[m] = ldf(tmpl, t * 64 + m * 8 + j, fF);
        float r = ldf(tmpl, t * 64 + j * 8 + m, fF);
        s += r * r;
      }
      f2h2 = s * 0.125f;
    }
    float hwr[LSZ], f1r[LSZ];
#pragma unroll
    for (int l = 0; l < LSZ; ++l) { hwr[l] = hwS[nb][l]; f1r[l] = f1S[nb][l]; }

    float Mc[LSZ];
    {
      float accI[LSZ];
#pragma unroll
      for (int l = 0; l < LSZ; ++l) accI[l] = 0.f;
      float tn2 = 0.f;
      const long tb = (long)local * HID;
      for (int kb = 0; kb < 8; ++kb) {
        float r[8];
#pragma unroll
        for (int q = 0; q < 8; ++q) r[q] = ldf(tfeat, tb + kb * 8 + q, fF);
#pragma unroll
        for (int q = 0; q < 8; ++q) tn2 += r[q] * r[q];
#pragma unroll
        for (int l = 0; l < LSZ; ++l) {
          float s = 0.f;
#pragma unroll
          for (int q = 0; q < 8; ++q) s += xlS[nb][l][kb * 8 + q] * r[q];
          accI[l] += s;
        }
      }
#pragma unroll
      for (int l = 0; l < LSZ; ++l)
        Mc[l] = xnS[nb][l] + tn2 - 2.f * accI[l];
    }

    float Tc[LSZ], Kc[LSZ], u[LSZ];
#pragma unroll
    for (int l = 0; l < LSZ; ++l) Tc[l] = hwr[l] * 0.125f;

    float v = 1.0f;
    for (int outer = 0; outer < 3; ++outer) {
      float Ac[LSZ];
#pragma unroll
      for (int l = 0; l < LSZ; ++l) {
        float s = 0.f;
#pragma unroll
        for (int l2 = 0; l2 < LSZ; ++l2) s += C1S[nb][l * LSZ + l2] * Tc[l2];
        Ac[l] = s;
      }
#pragma unroll
      for (int l = 0; l < LSZ; ++l) {
        float s = 0.f;
#pragma unroll
        for (int m = 0; m < NTN; ++m) s += __shfl(Ac[l], ob + m) * C2c[m];
        float tens = f1r[l] + f2h2 - 2.f * s;
        Kc[l] = __expf(-5.0f * (Mc[l] + tens));
      }
      v = 1.0f;
      for (int it = 0; it < 5; ++it) {
#pragma unroll
        for (int l = 0; l < LSZ; ++l) {
          float p = Kc[l] * v;
          p += __shfl_xor(p, 1); p += __shfl_xor(p, 2); p += __shfl_xor(p, 4);
          u[l] = hwr[l] * frcp(p + 1e-16f);
        }
        float s = 0.f;
#pragma unroll
        for (int l = 0; l < LSZ; ++l) s += Kc[l] * u[l];
        v = 0.125f * frcp(s + 1e-16f);
      }
#pragma unroll
      for (int l = 0; l < LSZ; ++l) Tc[l] = u[l] * Kc[l] * v;
    }

    {
      float Ac[LSZ];
#pragma unroll
      for (int l = 0; l < LSZ; ++l) {
        float s = 0.f;
#pragma unroll
        for (int l2 = 0; l2 < LSZ; ++l2) s += C1S[nb][l * LSZ + l2] * Tc[l2];
        Ac[l] = s;
      }
      float cl = 0.f;
#pragma unroll
      for (int l = 0; l < LSZ; ++l) {
        float s = 0.f;
#pragma unroll
        for (int m = 0; m < NTN; ++m) s += __shfl(Ac[l], ob + m) * C2c[m];
        float tens = f1r[l] + f2h2 - 2.f * s;
        cl += Tc[l] * 0.5f * (Mc[l] + tens);
      }
      cl += __shfl_xor(cl, 1); cl += __shfl_xor(cl, 2); cl += __shfl_xor(cl, 4);
      if (j == 0) distS[nb][t] = cl;
    }
  } else if (j == 0) {
    distS[nb][t] = 0.f;
  }
  __syncthreads();

  // epilogue: out[n] = relu([xl0, dist] @ Wlin + blin)
  if (local < NCLS) {
    int c = local;
    float acc = ldf(blin, c, fF);
#pragma unroll
    for (int k = 0; k < HID; ++k)
      acc += xlS[nb][0][k] * ldf(Wlin, k * NCLS + c, fF);
#pragma unroll
    for (int tt = 0; tt < NTPL; ++tt)
      acc += distS[nb][tt] * ldf(Wlin, (HID + tt) * NCLS + c, fF);
    float r = acc > 0.f ? acc : 0.f;
    if (fF) ((float*)out)[(long)n * NCLS + c] = r;
    else    ((bf16_t*)out)[(long)n * NCLS + c] = f2b(r);
  }
}

extern "C" void kernel_launch(void* const* d_in, const int* in_sizes, int n_in,
                              void* d_out, int out_size, void* d_ws, size_t ws_size,
                              hipStream_t stream) {
  (void)in_sizes; (void)n_in; (void)out_size; (void)ws_size;
  const void* x     = d_in[0];
  const void* ei    = d_in[1];
  const void* nbr   = d_in[2];
  const void* nmask = d_in[3];
  const void* Cl    = d_in[4];
  const void* W1    = d_in[5];
  const void* b1    = d_in[6];
  const void* W2    = d_in[7];
  const void* b2    = d_in[8];
  const void* tmpl  = d_in[9];
  const void* tfeat = d_in[10];
  const void* Wlin  = d_in[11];
  const void* blin  = d_in[12];

  // ws layout: flags int[4] | tn2min float[10] (slots 4..13) | pad | dinv | bufA | bufB
  int*   flags  = (int*)d_ws;
  float* tn2min = (float*)d_ws + 4;
  float* dinv   = (float*)d_ws + 16;
  float* bufA   = dinv + NN;
  float* bufB   = bufA + (long)NN * HID;

  probe_kernel<<<1, 128, 0, stream>>>(x, ei, tfeat, flags, tn2min);

  hipMemsetAsync(dinv, 0, NN * sizeof(float), stream);
  deg_kernel<<<(EE + 255) / 256, 256, 0, stream>>>(ei, dinv, flags);
  dinv_kernel<<<(NN + 255) / 256, 256, 0, stream>>>(dinv);

  gemm1_kernel<<<NN / 16, 256, 0, stream>>>(x, W1, bufA, flags);
  init_self_kernel<<<NN * HID / 256, 256, 0, stream>>>(bufA, dinv, bufB);
  agg_kernel<<<EE / 4, 256, 0, stream>>>(ei, bufA, dinv, bufB, flags);
  bias_relu_kernel<<<NN * HID / 256, 256, 0, stream>>>(bufB, b1, flags);

  gemm2_kernel<<<NN / 16, 256, 0, stream>>>(bufB, W2, bufA, flags);
  init_self_kernel<<<NN * HID / 256, 256, 0, stream>>>(bufA, dinv, bufB);
  agg_kernel<<<EE / 4, 256, 0, stream>>>(ei, bufA, dinv, bufB, flags);

  fgw_kernel<<<NN / NODES_PB, 320, 0, stream>>>(bufB, b2, nbr, nmask, Cl, tmpl,
                                                tfeat, Wlin, blin, d_out, flags,
                                                tn2min);
}

// Round 5
// 343.025 us; speedup vs baseline: 3.0960x; 1.4757x over previous
//
#include <hip/hip_runtime.h>

// OT_GNN: 2x GCN -> per-node fused-GW distance to 10 templates -> linear head.
// R5: (1) gemm1/gemm2 vectorized loads (ushort8 / float4) — kills the 2048
// broadcast scalar loads per wave; (2) fgw lazy staging: per-node norm table
// n2[] makes the K==0 certificate need only 9 gathered scalars, full staging
// only on certificate failure (~never); (3) scatter-atomic aggregation
// replaced by device-built bucket lists + register gather (no float atomics),
// with init_self/bias_relu fused in.
// Certificate (R4): K = exp(-5(M+tens)) == 0 exactly in fp32 when
// (sqrt(tn2min)-sqrt(xn2max))^2 >= 26, since tens >= -2. => dist == 0 exact.

#define NN   20000
#define EE   320000
#define FIN  512
#define HID  64
#define KNEI 8
#define LSZ  9      // K_NEI + 1
#define NTPL 10
#define NTN  8
#define NCLS 6
#define CAP  48     // bucket capacity per node (max in-degree ~34)

typedef unsigned short bf16_t;
typedef unsigned short us8 __attribute__((ext_vector_type(8)));

__device__ __forceinline__ float b2f(bf16_t u) {
  union { unsigned int i; float f; } v; v.i = ((unsigned int)u) << 16; return v.f;
}
__device__ __forceinline__ bf16_t f2b(float f) {
  union { float f; unsigned int i; } v; v.f = f;
  unsigned int x = v.i;
  return (bf16_t)((x + 0x7fffu + ((x >> 16) & 1u)) >> 16);  // RNE
}
__device__ __forceinline__ float ldf(const void* p, long i, int fp32) {
  return fp32 ? ((const float*)p)[i] : b2f(((const bf16_t*)p)[i]);
}
__device__ __forceinline__ int ldi(const void* p, long i, int i64) {
  return i64 ? (int)((const long long*)p)[i] : ((const int*)p)[i];
}
__device__ __forceinline__ float frcp(float x) { return __builtin_amdgcn_rcpf(x); }

// ---------- dtype probe + template row-norm mins ----------
__global__ __launch_bounds__(128) void probe_kernel(const void* __restrict__ x,
                                                    const void* __restrict__ ei,
                                                    const void* __restrict__ tfeat,
                                                    int* __restrict__ flags,
                                                    float* __restrict__ tn2min) {
  __shared__ int sfl[2];
  __shared__ float tn2s[80];
  int tid = threadIdx.x;
  if (tid == 0) {
    int sane = 0;
    for (int k = 0; k < 64; k += 2) {
      bf16_t u = ((const bf16_t*)x)[k];
      int e = (u >> 7) & 0xff;
      if (e >= 112 && e <= 142) sane++;
    }
    int f0 = (sane < 24) ? 1 : 0;
    int zc = 0;
    for (int k = 1; k < 64; k += 2)
      if (((const int*)ei)[k] == 0) zc++;
    int f1 = (zc >= 16) ? 1 : 0;
    flags[0] = f0; flags[1] = f1;
    sfl[0] = f0; sfl[1] = f1;
  }
  __syncthreads();
  if (tid < 80) {
    int fF = sfl[0];
    float s = 0.f;
    for (int k = 0; k < HID; ++k) {
      float v = ldf(tfeat, (long)tid * HID + k, fF);
      s += v * v;
    }
    tn2s[tid] = s;
  }
  __syncthreads();
  if (tid == 0) {
    float gmin = 1e30f;
    for (int t = 0; t < NTPL; ++t) {
      float m = tn2s[t * 8];
      for (int r = 1; r < 8; ++r) m = fminf(m, tn2s[t * 8 + r]);
      tn2min[t] = m;
      gmin = fminf(gmin, m);
    }
    tn2min[NTPL] = gmin;
  }
}

// ---------- in-degree histogram ----------
__global__ __launch_bounds__(256) void hist_kernel(const void* __restrict__ ei,
                                                   int* __restrict__ cnt,
                                                   const int* __restrict__ flags) {
  int i = blockIdx.x * 256 + threadIdx.x;
  if (i < EE) atomicAdd(&cnt[ldi(ei, (long)EE + i, flags[1])], 1);
}
__global__ __launch_bounds__(256) void dinv_kernel(const int* __restrict__ cnt,
                                                   float* __restrict__ dinv) {
  int i = blockIdx.x * 256 + threadIdx.x;
  if (i < NN) dinv[i] = rsqrtf((float)cnt[i] + 1.0f);   // +1 self loop
}

// ---------- bucket scatter: slot[d*CAP + pos] = src ----------
__global__ __launch_bounds__(256) void scatter_kernel(const void* __restrict__ ei,
                                                      int* __restrict__ pos,
                                                      int* __restrict__ slot,
                                                      const int* __restrict__ flags) {
  int i = blockIdx.x * 256 + threadIdx.x;
  if (i >= EE) return;
  int i64 = flags[1];
  int s = ldi(ei, i, i64);
  int d = ldi(ei, (long)EE + i, i64);
  int p = atomicAdd(&pos[d], 1);
  if (p < CAP) slot[d * CAP + p] = s;
}

// ---------- GEMM1: xw1 = x @ W1 (vectorized x loads) ----------
__global__ __launch_bounds__(256) void gemm1_kernel(const void* __restrict__ x,
                                                    const void* __restrict__ W1,
                                                    float* __restrict__ xw1,
                                                    const int* __restrict__ flags) {
  int wave = blockIdx.x * 4 + (threadIdx.x >> 6);
  int lane = threadIdx.x & 63;
  int row0 = wave * 4;                      // 1250 blocks * 4 waves * 4 rows
  if (row0 >= NN) return;
  float a0 = 0.f, a1 = 0.f, a2 = 0.f, a3 = 0.f;
  if (!flags[0]) {
    const bf16_t* xb = (const bf16_t*)x + (long)row0 * FIN;
    const bf16_t* wp = (const bf16_t*)W1;
#pragma unroll 2
    for (int k8 = 0; k8 < FIN / 8; ++k8) {
      us8 r0 = *(const us8*)(xb + k8 * 8);
      us8 r1 = *(const us8*)(xb + FIN + k8 * 8);
      us8 r2 = *(const us8*)(xb + 2 * FIN + k8 * 8);
      us8 r3 = *(const us8*)(xb + 3 * FIN + k8 * 8);
#pragma unroll
      for (int q = 0; q < 8; ++q) {
        float w = b2f(wp[(k8 * 8 + q) * HID + lane]);
        a0 += b2f(r0[q]) * w;
        a1 += b2f(r1[q]) * w;
        a2 += b2f(r2[q]) * w;
        a3 += b2f(r3[q]) * w;
      }
    }
  } else {
    const float* x0 = (const float*)x + (long)row0 * FIN;
    const float* wp = (const float*)W1;
#pragma unroll 8
    for (int k = 0; k < FIN; ++k) {
      float w = wp[k * HID + lane];
      a0 += x0[k] * w;
      a1 += x0[FIN + k] * w;
      a2 += x0[2 * FIN + k] * w;
      a3 += x0[3 * FIN + k] * w;
    }
  }
  xw1[(long)(row0 + 0) * HID + lane] = a0;
  xw1[(long)(row0 + 1) * HID + lane] = a1;
  xw1[(long)(row0 + 2) * HID + lane] = a2;
  xw1[(long)(row0 + 3) * HID + lane] = a3;
}

// ---------- GEMM2: xw2 = h1 @ W2 (float4 h loads) ----------
__global__ __launch_bounds__(256) void gemm2_kernel(const float* __restrict__ h,
                                                    const void* __restrict__ W2,
                                                    float* __restrict__ xw2,
                                                    const int* __restrict__ flags) {
  int wave = blockIdx.x * 4 + (threadIdx.x >> 6);
  int lane = threadIdx.x & 63;
  int row0 = wave * 4;
  if (row0 >= NN) return;
  int fF = flags[0];
  float a0 = 0.f, a1 = 0.f, a2 = 0.f, a3 = 0.f;
  const float* h0 = h + (long)row0 * HID;
#pragma unroll 4
  for (int k4 = 0; k4 < HID / 4; ++k4) {
    float4 r0 = *(const float4*)(h0 + k4 * 4);
    float4 r1 = *(const float4*)(h0 + HID + k4 * 4);
    float4 r2 = *(const float4*)(h0 + 2 * HID + k4 * 4);
    float4 r3 = *(const float4*)(h0 + 3 * HID + k4 * 4);
#pragma unroll
    for (int q = 0; q < 4; ++q) {
      float w = ldf(W2, (k4 * 4 + q) * HID + lane, fF);
      float e0 = (q == 0) ? r0.x : (q == 1) ? r0.y : (q == 2) ? r0.z : r0.w;
      float e1 = (q == 0) ? r1.x : (q == 1) ? r1.y : (q == 2) ? r1.z : r1.w;
      float e2 = (q == 0) ? r2.x : (q == 1) ? r2.y : (q == 2) ? r2.z : r2.w;
      float e3 = (q == 0) ? r3.x : (q == 1) ? r3.y : (q == 2) ? r3.z : r3.w;
      a0 += e0 * w; a1 += e1 * w; a2 += e2 * w; a3 += e3 * w;
    }
  }
  xw2[(long)(row0 + 0) * HID + lane] = a0;
  xw2[(long)(row0 + 1) * HID + lane] = a1;
  xw2[(long)(row0 + 2) * HID + lane] = a2;
  xw2[(long)(row0 + 3) * HID + lane] = a3;
}

// ---------- GCN aggregation via bucket gather (fuses self term + bias/relu) --
__global__ __launch_bounds__(256) void gather_kernel(const float* __restrict__ xw,
                                                     const float* __restrict__ dinv,
                                                     const int* __restrict__ cnt,
                                                     const int* __restrict__ slot,
                                                     float* __restrict__ h,
                                                     const void* __restrict__ bias,
                                                     const int* __restrict__ flags,
                                                     int relu_bias) {
  int n = blockIdx.x * 4 + (threadIdx.x >> 6);
  if (n >= NN) return;
  int c = threadIdx.x & 63;
  float dn = dinv[n];
  float acc = xw[(long)n * HID + c] * dn;      // self term (xw[n]*dinv[n])
  int m = cnt[n]; if (m > CAP) m = CAP;
  const int* sl = slot + (long)n * CAP;
  int sN = (m > 0) ? sl[0] : 0;
  for (int e = 0; e < m; ++e) {
    int s = sN;
    if (e + 1 < m) sN = sl[e + 1];
    acc += xw[(long)s * HID + c] * dinv[s];
  }
  acc *= dn;                                    // h = dinv[n]*(sum + self*dinv[n])
  if (relu_bias) {
    acc += ldf(bias, c, flags[0]);
    acc = acc > 0.f ? acc : 0.f;
  }
  h[(long)n * HID + c] = acc;
}

// ---------- per-node squared norm of (h2 + b2) ----------
__global__ __launch_bounds__(256) void norms_kernel(const float* __restrict__ h2,
                                                    const void* __restrict__ b2v,
                                                    float* __restrict__ n2,
                                                    const int* __restrict__ flags) {
  int n = blockIdx.x * 4 + (threadIdx.x >> 6);
  if (n >= NN) return;
  int c = threadIdx.x & 63;
  float v = h2[(long)n * HID + c] + ldf(b2v, c, flags[0]);
  float s = v * v;
  s += __shfl_xor(s, 1); s += __shfl_xor(s, 2); s += __shfl_xor(s, 4);
  s += __shfl_xor(s, 8); s += __shfl_xor(s, 16); s += __shfl_xor(s, 32);
  if (c == 0) n2[n] = s;
}

// ---------- FGW: 4 nodes/block, 8-lane octet per (node, template) ----------
#define NODES_PB 4
#define TPN 80            // threads per node (10 templates x 8 lanes)
#define XLP 65            // padded xl row stride

__global__ __launch_bounds__(320, 2) void fgw_kernel(
    const float* __restrict__ h2,        // [NN,64] fp32 ws (pre-b2)
    const void* __restrict__ b2v,
    const void* __restrict__ nbr_idx,
    const void* __restrict__ nbr_mask,
    const void* __restrict__ C_local,
    const void* __restrict__ tmpl,       // [10,8,8]
    const void* __restrict__ tfeat,      // [10,8,64]
    const void* __restrict__ Wlin,       // [74,6]
    const void* __restrict__ blin,       // [6]
    void* __restrict__ out,              // [NN,6]
    const int* __restrict__ flags,
    const float* __restrict__ tn2min,    // [11]: per-t mins + global min
    const float* __restrict__ n2)        // [NN] node norm^2
{
  const int tid = threadIdx.x;
  const int fF = flags[0];
  const int fI = flags[1];
  const int nb = tid / TPN;
  const int local = tid - nb * TPN;      // [0,80)
  const int t = local >> 3;
  const int j = local & 7;
  const int n = blockIdx.x * NODES_PB + nb;
  const int lane = tid & 63;
  const int ob = lane & 56;

  __shared__ float xlS[NODES_PB][LSZ][XLP];
  __shared__ float C1S[NODES_PB][81];
  __shared__ float hwS[NODES_PB][LSZ];
  __shared__ float f1S[NODES_PB][LSZ];
  __shared__ float xnS[NODES_PB][LSZ];
  __shared__ float distS[NODES_PB][NTPL];
  __shared__ float xmaxS[NODES_PB];
  __shared__ int   needS[NODES_PB];
  __shared__ int   sidxS[NODES_PB][LSZ];

  // phase 1: neighbor indices + gathered norms (same thread writes+reads)
  if (local < LSZ) {
    int idx = (local == 0) ? n : ldi(nbr_idx, (long)n * KNEI + local - 1, fI);
    sidxS[nb][local] = idx;
    xnS[nb][local] = n2[idx];
  }
  // self row staged unconditionally (needed by epilogue)
  if (local < HID)
    xlS[nb][0][local] = h2[(long)n * HID + local] + ldf(b2v, local, fF);
  __syncthreads();   // B1: xnS, sidxS visible

  if (local == 0) {
    float xm = xnS[nb][0];
#pragma unroll
    for (int l = 1; l < LSZ; ++l) xm = fmaxf(xm, xnS[nb][l]);
    xmaxS[nb] = xm;
    needS[nb] = ((sqrtf(tn2min[NTPL]) - sqrtf(xm)) >= 5.0990195f) ? 0 : 1;
  }
  __syncthreads();   // B2: needS, xmaxS visible

  const int need = needS[nb];
  if (need) {
    for (int i = local; i < 8 * HID; i += TPN) {
      int l = 1 + (i >> 6), k = i & 63;
      xlS[nb][l][k] = h2[(long)sidxS[nb][l] * HID + k] + ldf(b2v, k, fF);
    }
    for (int i = local; i < 81; i += TPN)
      C1S[nb][i] = ldf(C_local, (long)n * 81 + i, fF);
  }
  __syncthreads();   // B3

  if (need && local < LSZ) {
    int l = local;
    float msum = 0.f, f1 = 0.f;
#pragma unroll
    for (int jj = 0; jj < LSZ; ++jj) {
      float mj = ldf(nbr_mask, (long)n * LSZ + jj, fF);
      msum += mj;
      float c = C1S[nb][l * LSZ + jj];
      f1 += c * c * mj;
    }
    float inv = frcp(msum);
    hwS[nb][l] = ldf(nbr_mask, (long)n * LSZ + l, fF) * inv;
    f1S[nb][l] = f1 * inv;
  }
  __syncthreads();   // B4

  bool slow = need && ((sqrtf(tn2min[t]) - sqrtf(xmaxS[nb])) < 5.0990195f);
  if (slow) {
    // ---------- faithful register-resident FGW (R3 path) ----------
    float C2c[NTN];
    float f2h2;
    {
      float s = 0.f;
#pragma unroll
      for (int m = 0; m < NTN; ++m) {
        C2c[m] = ldf(tmpl, t * 64 + m * 8 + j, fF);
        float r = ldf(tmpl, t * 64 + j * 8 + m, fF);
        s += r * r;
      }
      f2h2 = s * 0.125f;
    }
    float hwr[LSZ], f1r[LSZ];
#pragma unroll
    for (int l = 0; l < LSZ; ++l) { hwr[l] = hwS[nb][l]; f1r[l] = f1S[nb][l]; }

    float Mc[LSZ];
    {
      float accI[LSZ];
#pragma unroll
      for (int l = 0; l < LSZ; ++l) accI[l] = 0.f;
      float tn2 = 0.f;
      const long tb = (long)local * HID;
      for (int kb = 0; kb < 8; ++kb) {
        float r[8];
#pragma unroll
        for (int q = 0; q < 8; ++q) r[q] = ldf(tfeat, tb + kb * 8 + q, fF);
#pragma unroll
        for (int q = 0; q < 8; ++q) tn2 += r[q] * r[q];
#pragma unroll
        for (int l = 0; l < LSZ; ++l) {
          float s = 0.f;
#pragma unroll
          for (int q = 0; q < 8; ++q) s += xlS[nb][l][kb * 8 + q] * r[q];
          accI[l] += s;
        }
      }
#pragma unroll
      for (int l = 0; l < LSZ; ++l)
        Mc[l] = xnS[nb][l] + tn2 - 2.f * accI[l];
    }

    float Tc[LSZ], Kc[LSZ], u[LSZ];
#pragma unroll
    for (int l = 0; l < LSZ; ++l) Tc[l] = hwr[l] * 0.125f;

    float v = 1.0f;
    for (int outer = 0; outer < 3; ++outer) {
      float Ac[LSZ];
#pragma unroll
      for (int l = 0; l < LSZ; ++l) {
        float s = 0.f;
#pragma unroll
        for (int l2 = 0; l2 < LSZ; ++l2) s += C1S[nb][l * LSZ + l2] * Tc[l2];
        Ac[l] = s;
      }
#pragma unroll
      for (int l = 0; l < LSZ; ++l) {
        float s = 0.f;
#pragma unroll
        for (int m = 0; m < NTN; ++m) s += __shfl(Ac[l], ob + m) * C2c[m];
        float tens = f1r[l] + f2h2 - 2.f * s;
        Kc[l] = __expf(-5.0f * (Mc[l] + tens));
      }
      v = 1.0f;
      for (int it = 0; it < 5; ++it) {
#pragma unroll
        for (int l = 0; l < LSZ; ++l) {
          float p = Kc[l] * v;
          p += __shfl_xor(p, 1); p += __shfl_xor(p, 2); p += __shfl_xor(p, 4);
          u[l] = hwr[l] * frcp(p + 1e-16f);
        }
        float s = 0.f;
#pragma unroll
        for (int l = 0; l < LSZ; ++l) s += Kc[l] * u[l];
        v = 0.125f * frcp(s + 1e-16f);
      }
#pragma unroll
      for (int l = 0; l < LSZ; ++l) Tc[l] = u[l] * Kc[l] * v;
    }
    {
      float Ac[LSZ];
#pragma unroll
      for (int l = 0; l < LSZ; ++l) {
        float s = 0.f;
#pragma unroll
        for (int l2 = 0; l2 < LSZ; ++l2) s += C1S[nb][l * LSZ + l2] * Tc[l2];
        Ac[l] = s;
      }
      float cl = 0.f;
#pragma unroll
      for (int l = 0; l < LSZ; ++l) {
        float s = 0.f;
#pragma unroll
        for (int m = 0; m < NTN; ++m) s += __shfl(Ac[l], ob + m) * C2c[m];
        float tens = f1r[l] + f2h2 - 2.f * s;
        cl += Tc[l] * 0.5f * (Mc[l] + tens);
      }
      cl += __shfl_xor(cl, 1); cl += __shfl_xor(cl, 2); cl += __shfl_xor(cl, 4);
      if (j == 0) distS[nb][t] = cl;
    }
  } else if (j == 0) {
    distS[nb][t] = 0.f;
  }
  __syncthreads();   // B5

  // epilogue: out[n] = relu([xl0, dist] @ Wlin + blin)
  if (local < NCLS) {
    int c = local;
    float acc = ldf(blin, c, fF);
#pragma unroll
    for (int k = 0; k < HID; ++k)
      acc += xlS[nb][0][k] * ldf(Wlin, k * NCLS + c, fF);
#pragma unroll
    for (int tt = 0; tt < NTPL; ++tt)
      acc += distS[nb][tt] * ldf(Wlin, (HID + tt) * NCLS + c, fF);
    float r = acc > 0.f ? acc : 0.f;
    if (fF) ((float*)out)[(long)n * NCLS + c] = r;
    else    ((bf16_t*)out)[(long)n * NCLS + c] = f2b(r);
  }
}

extern "C" void kernel_launch(void* const* d_in, const int* in_sizes, int n_in,
                              void* d_out, int out_size, void* d_ws, size_t ws_size,
                              hipStream_t stream) {
  (void)in_sizes; (void)n_in; (void)out_size; (void)ws_size;
  const void* x     = d_in[0];
  const void* ei    = d_in[1];
  const void* nbr   = d_in[2];
  const void* nmask = d_in[3];
  const void* Cl    = d_in[4];
  const void* W1    = d_in[5];
  const void* b1    = d_in[6];
  const void* W2    = d_in[7];
  const void* b2    = d_in[8];
  const void* tmpl  = d_in[9];
  const void* tfeat = d_in[10];
  const void* Wlin  = d_in[11];
  const void* blin  = d_in[12];

  // ws layout (4B words): flags[4] | tn2min[12] | dinv NN | n2 NN | cnt NN |
  //                       pos NN | slot CAP*NN | bufA 64NN | bufB 64NN
  int*   flags  = (int*)d_ws;
  float* tn2min = (float*)d_ws + 4;
  float* dinv   = (float*)d_ws + 16;
  float* n2     = dinv + NN;
  int*   cnt    = (int*)(n2 + NN);
  int*   pos    = cnt + NN;
  int*   slot   = pos + NN;
  float* bufA   = (float*)(slot + (long)CAP * NN);
  float* bufB   = bufA + (long)NN * HID;

  probe_kernel<<<1, 128, 0, stream>>>(x, ei, tfeat, flags, tn2min);

  hipMemsetAsync(cnt, 0, NN * sizeof(int), stream);
  hipMemsetAsync(pos, 0, NN * sizeof(int), stream);
  hist_kernel<<<(EE + 255) / 256, 256, 0, stream>>>(ei, cnt, flags);
  dinv_kernel<<<(NN + 255) / 256, 256, 0, stream>>>(cnt, dinv);
  scatter_kernel<<<(EE + 255) / 256, 256, 0, stream>>>(ei, pos, slot, flags);

  // layer 1
  gemm1_kernel<<<NN / 16, 256, 0, stream>>>(x, W1, bufA, flags);
  gather_kernel<<<NN / 4, 256, 0, stream>>>(bufA, dinv, cnt, slot, bufB,
                                            b1, flags, 1);
  // layer 2
  gemm2_kernel<<<NN / 16, 256, 0, stream>>>(bufB, W2, bufA, flags);
  gather_kernel<<<NN / 4, 256, 0, stream>>>(bufA, dinv, cnt, slot, bufB,
                                            b2, flags, 0);

  norms_kernel<<<NN / 4, 256, 0, stream>>>(bufB, b2, n2, flags);

  fgw_kernel<<<NN / NODES_PB, 320, 0, stream>>>(bufB, b2, nbr, nmask, Cl, tmpl,
                                                tfeat, Wlin, blin, d_out, flags,
                                                tn2min, n2);
}